// Round 19
// baseline (1702.994 us; speedup 1.0000x reference)
//
#include <hip/hip_runtime.h>

#define ENCD 2048
#define ATTD 512
#define HIDD 512
#define NB 64
#define NP 196
#define NT 20
#define NV 32000
#define NE 512

using s8v = __attribute__((ext_vector_type(8))) short;   // 8 bf16 (4 VGPRs)
using f4v = __attribute__((ext_vector_type(4))) float;   // 4 f32 acc
#define MFMA_B16 __builtin_amdgcn_mfma_f32_16x16x32_bf16

__device__ inline short f2b(float f) {
  union { float f; unsigned u; } v; v.f = f;
  unsigned r = v.u + 0x7fff + ((v.u >> 16) & 1);
  return (short)(r >> 16);
}
__device__ inline float b2f(short s) {
  union { unsigned u; float f; } v; v.u = ((unsigned)(unsigned short)s) << 16;
  return v.f;
}

// ------- fused: enc f32 -> encB bf16, and mean over P -> meB[b][k] -------
__global__ void conv_mean(const float* __restrict__ enc, short* __restrict__ encB,
                          short* __restrict__ meB) {
  int b = blockIdx.x >> 2, kq = blockIdx.x & 3;
  int k = kq * 512 + threadIdx.x * 2;
  const float* src = enc + (size_t)b * NP * ENCD + k;
  short* dst = encB + (size_t)b * NP * ENCD + k;
  float a0 = 0.f, a1 = 0.f;
  for (int p = 0; p < NP; ++p) {
    float2 v = *(const float2*)(src + (size_t)p * ENCD);
    a0 += v.x; a1 += v.y;
    short2 o; o.x = f2b(v.x); o.y = f2b(v.y);
    *(short2*)(dst + (size_t)p * ENCD) = o;
  }
  short2 m; m.x = f2b(a0 * (1.f / NP)); m.y = f2b(a1 * (1.f / NP));
  *(short2*)(meB + (size_t)b * ENCD + k) = m;
}

// ---------------- embedding gather -> bf16 row-major embB[t][b][k] ----------------
__global__ void emb_b16(const int* __restrict__ caps, const float* __restrict__ emb,
                        short* __restrict__ embB) {
  int t = blockIdx.x / NB, b = blockIdx.x % NB;
  int cap = caps[b * NT + t];
  int k = threadIdx.x;
  for (int r = 0; r < 2; ++r, k += 256)
    embB[((size_t)t * NB + b) * NE + k] = f2b(emb[(size_t)cap * NE + k]);
}

// ---- swizzle builder: B[k][n] f32 row-major (ld = N) -> MFMA b-frag layout
__global__ void swz_rm(const float* __restrict__ B, int N, short* __restrict__ dst) {
  __shared__ short lt[256 * 32];          // [n within chunk][k]
  int tid = threadIdx.x;
  int k0 = blockIdx.x * 32, n0 = blockIdx.y * 256;
  for (int k = 0; k < 32; ++k)
    lt[tid * 32 + k] = f2b(B[(size_t)(k0 + k) * N + n0 + tid]);
  __syncthreads();
  int NT16 = N >> 4;
  for (int r = 0; r < 4; ++r) {
    int idx = r * 256 + tid;
    int lane = idx & 63, ntl = idx >> 6;
    int srcn = ntl * 16 + (lane & 15), srck = (lane >> 4) * 8;
    short* o = dst + ((size_t)blockIdx.x * NT16 + (n0 >> 4) + ntl) * 512 + lane * 8;
    for (int i = 0; i < 8; ++i) o[i] = lt[srcn * 32 + srck + i];
  }
}

// ---- two 2048x512 swizzles in one dispatch (z selects src/dst) ----
__global__ void swz_rm2(const float* __restrict__ B0, short* __restrict__ D0,
                        const float* __restrict__ B1, short* __restrict__ D1) {
  __shared__ short lt[256 * 32];
  const float* B = blockIdx.z ? B1 : B0;
  short* dst = blockIdx.z ? D1 : D0;
  int tid = threadIdx.x;
  int k0 = blockIdx.x * 32, n0 = blockIdx.y * 256;
  for (int k = 0; k < 32; ++k)
    lt[tid * 32 + k] = f2b(B[(size_t)(k0 + k) * 512 + n0 + tid]);
  __syncthreads();
  for (int r = 0; r < 4; ++r) {
    int idx = r * 256 + tid;
    int lane = idx & 63, ntl = idx >> 6;
    int srcn = ntl * 16 + (lane & 15), srck = (lane >> 4) * 8;
    short* o = dst + ((size_t)blockIdx.x * 32 + (n0 >> 4) + ntl) * 512 + lane * 8;
    for (int i = 0; i < 8; ++i) o[i] = lt[srcn * 32 + srck + i];
  }
}

// ---- LSTM combined weight swizzle ----
__global__ void swz_lstm(const float* __restrict__ Wih, int Kih, const float* __restrict__ Whh,
                         short* __restrict__ dst) {
  int tid = threadIdx.x, lane = tid & 63;
  int ct = blockIdx.y * 4 + (tid >> 6);
  int n = ct * 16 + (lane & 15);
  int k = blockIdx.x * 32 + ((lane >> 4) << 3);
  short* o = dst + ((size_t)blockIdx.x * 128 + ct) * 512 + lane * 8;
  for (int i = 0; i < 8; ++i) {
    int kk = k + i;
    float f = (kk < Kih) ? Wih[(size_t)n * Kih + kk] : Whh[(size_t)n * 512 + (kk - Kih)];
    o[i] = f2b(f);
  }
}

// ---- both bias sums in one dispatch ----
__global__ void bias_sum2(const float* __restrict__ a0, const float* __restrict__ b0,
                          float* __restrict__ o0,
                          const float* __restrict__ a1, const float* __restrict__ b1,
                          float* __restrict__ o1) {
  int i = (blockIdx.x & 7) * 256 + threadIdx.x;
  if (blockIdx.x < 8) o0[i] = a0[i] + b0[i];
  else                o1[i] = a1[i] + b1[i];
}

// ------- att1 = encB @ WeaS + bea -> bf16 [12544][512] -------
// 196 blocks (one 64-row A panel each, read ONCE), LDS double-buffered A
__global__ void __launch_bounds__(256) att1_tiled(
    const short* __restrict__ A, const short* __restrict__ Bs,
    const float* __restrict__ bias, short* __restrict__ att1B) {
  __shared__ short as[2][64][40];         // padded: row stride 80B -> 2-way bank alias only
  int tid = threadIdx.x, lane = tid & 63, w = tid >> 6;
  int m0 = blockIdx.x * 64;
  int mrow = lane & 15, kq = lane >> 4;
  int sr = tid >> 2, sc = (tid & 3) * 8;
  f4v acc[4][8] = {};
  *(s8v*)&as[0][sr][sc] = *(const s8v*)(A + (size_t)(m0 + sr) * 2048 + sc);
  __syncthreads();
  for (int ks = 0; ks < 64; ++ks) {
    int cur = ks & 1;
    if (ks < 63)
      *(s8v*)&as[cur ^ 1][sr][sc] = *(const s8v*)(A + (size_t)(m0 + sr) * 2048 + (ks + 1) * 32 + sc);
    s8v a[4], b[8];
#pragma unroll
    for (int mi = 0; mi < 4; ++mi)
      a[mi] = *(const s8v*)&as[cur][mi * 16 + mrow][kq * 8];
#pragma unroll
    for (int ni = 0; ni < 8; ++ni)
      b[ni] = *(const s8v*)(Bs + ((size_t)ks * 32 + w * 8 + ni) * 512 + lane * 8);
#pragma unroll
    for (int mi = 0; mi < 4; ++mi)
#pragma unroll
      for (int ni = 0; ni < 8; ++ni)
        acc[mi][ni] = MFMA_B16(a[mi], b[ni], acc[mi][ni], 0, 0, 0);
    __syncthreads();
  }
#pragma unroll
  for (int mi = 0; mi < 4; ++mi)
#pragma unroll
    for (int ni = 0; ni < 8; ++ni) {
      int col = (w * 8 + ni) * 16 + mrow;
      int rbase = m0 + mi * 16 + kq * 4;
      float bv = bias[col];
      for (int r = 0; r < 4; ++r)
        att1B[(size_t)(rbase + r) * 512 + col] = f2b(acc[mi][ni][r] + bv);
    }
}

// ---- init h/c via MFMA ----
__global__ void init_mfma(const short* __restrict__ A,
                          const short* __restrict__ BsH, const short* __restrict__ BsC,
                          const float* __restrict__ bih, const float* __restrict__ bic,
                          short* __restrict__ h0, short* __restrict__ h1,
                          float* __restrict__ c0v, float* __restrict__ c1v) {
  int lane = threadIdx.x & 63;
  int mi = blockIdx.x, jt0 = blockIdx.y;
  bool isC = jt0 >= 32;
  int jt = jt0 & 31;
  const short* Bs = isC ? BsC : BsH;
  int mrow = lane & 15, kq = lane >> 4;
  f4v acc = {};
  const short* aBase = A + (size_t)(mi * 16 + mrow) * 2048 + kq * 8;
  const short* bBase = Bs + lane * 8;
#pragma unroll 4
  for (int ks = 0; ks < 64; ++ks) {
    s8v a = *(const s8v*)(aBase + ks * 32);
    s8v b = *(const s8v*)(bBase + ((size_t)ks * 32 + jt) * 512);
    acc = MFMA_B16(a, b, acc, 0, 0, 0);
  }
  int j = jt * 16 + mrow;
  float bv = (isC ? bic : bih)[j];
  for (int r = 0; r < 4; ++r) {
    int b = mi * 16 + kq * 4 + r;
    size_t idx = (size_t)b * 512 + j;
    float o = acc[r] + bv;
    if (isC) { c0v[idx] = o; c1v[idx] = o; }
    else     { short s = f2b(o); h0[idx] = s; h1[idx] = s; }
  }
}

// ---- compile-time K-segment for the LSTM gates GEMM (enables unroll/pipelining) ----
template<int KSEG, int KBASE>
__device__ __forceinline__ void seg_mm(const short* __restrict__ aRow, int kh, int kq,
                                       int ct, const short* __restrict__ bBase, f4v& acc) {
  constexpr int HALF = KSEG / 2;
  const int kl0 = kh * HALF;
#pragma unroll 4
  for (int i = 0; i < HALF / 32; ++i) {
    int kl = kl0 + i * 32;
    s8v a = *(const s8v*)(aRow + kl + kq * 8);
    int ksi = (KBASE + kl) >> 5;
    s8v b = *(const s8v*)(bBase + ((size_t)ksi * 128 + ct) * 512);
    acc = MFMA_B16(a, b, acc, 0, 0, 0);
  }
}

// ------- fused LSTM: 8-wave (gate g x k-half kh) split-K; 512 thr; templated K -------
// grid(32, 4): jt = x (fastest) so same-B blocks land on the same XCD.
template<int K1, int K2, int K3>
__global__ void __launch_bounds__(512) lstm_t(
    const short* __restrict__ A1, const short* __restrict__ A2,
    const short* __restrict__ A3,
    const short* __restrict__ Bs, const float* __restrict__ bias,
    float* __restrict__ c_st, short* __restrict__ h_out) {
  __shared__ f4v gsh[8][64];
  int tid = threadIdx.x, lane = tid & 63, w = tid >> 6;
  int g = w >> 1, kh = w & 1;
  int jt = blockIdx.x, mi = blockIdx.y;
  int mrow = lane & 15, kq = lane >> 4;
  int m = mi * 16 + mrow;
  int ct = g * 32 + jt;
  f4v acc = {};
  const short* bBase = Bs + lane * 8;
  seg_mm<K1, 0>(A1 + (size_t)m * K1, kh, kq, ct, bBase, acc);
  seg_mm<K2, K1>(A2 + (size_t)m * K2, kh, kq, ct, bBase, acc);
  if constexpr (K3 > 0)
    seg_mm<K3, K1 + K2>(A3 + (size_t)m * K3, kh, kq, ct, bBase, acc);
  gsh[w][lane] = acc;
  __syncthreads();
  if (tid < 256) {
    int b_l = tid >> 4, j_l = tid & 15;
    int lsrc = (b_l >> 2) * 16 + j_l, r = b_l & 3;
    int j = jt * 16 + j_l;
    float ii = gsh[0][lsrc][r] + gsh[1][lsrc][r] + bias[j];
    float ff = gsh[2][lsrc][r] + gsh[3][lsrc][r] + bias[512 + j];
    float gg = gsh[4][lsrc][r] + gsh[5][lsrc][r] + bias[1024 + j];
    float oo = gsh[6][lsrc][r] + gsh[7][lsrc][r] + bias[1536 + j];
    size_t idx = (size_t)(mi * 16 + b_l) * 512 + j;
    float c_old = c_st[idx];
    float si = 1.f / (1.f + expf(-ii));
    float sf = 1.f / (1.f + expf(-ff));
    float so = 1.f / (1.f + expf(-oo));
    float cn = sf * c_old + si * tanhf(gg);
    c_st[idx] = cn;
    h_out[idx] = f2b(so * tanhf(cn));
  }
}

// ------- att2 = h1 @ WdaS + bda -> f32 [64][512]; 256-thr, wave = mi -------
__global__ void att2_mfma(const short* __restrict__ A, const short* __restrict__ Bs,
                          const float* __restrict__ bias, float* __restrict__ C) {
  int tid = threadIdx.x, lane = tid & 63, mi = tid >> 6;
  int nt = blockIdx.x;
  int mrow = lane & 15, kq = lane >> 4;
  f4v acc = {};
  const short* aBase = A + (size_t)(mi * 16 + mrow) * 512 + kq * 8;
  const short* bBase = Bs + lane * 8;
#pragma unroll
  for (int ks = 0; ks < 16; ++ks) {
    s8v a = *(const s8v*)(aBase + ks * 32);
    s8v b = *(const s8v*)(bBase + ((size_t)ks * 32 + nt) * 512);
    acc = MFMA_B16(a, b, acc, 0, 0, 0);
  }
  int col = nt * 16 + mrow;
  float bv = bias[col];
  for (int r = 0; r < 4; ++r) C[(size_t)(mi * 16 + kq * 4 + r) * 512 + col] = acc[r] + bv;
}

// ------- fused e-score + softmax + awe: 256 blocks (b x 4 dq), 256 thr -------
// e/softmax computed redundantly per dq (cheap: att1B slice is L2-resident, ~1 us);
// awe keeps full 256-block parallelism on the 51 MB encB stream.
__global__ void esc_smax_awe(const short* __restrict__ att1B, const float* __restrict__ att2,
                             const float* __restrict__ Wfa, const float* __restrict__ bfa,
                             const short* __restrict__ encB, short* __restrict__ aweB) {
  __shared__ float att2s[512];
  __shared__ float wfas[512];
  __shared__ float es[256];
  __shared__ float red[256];
  int b = blockIdx.x >> 2, dq = blockIdx.x & 3, tid = threadIdx.x;
  int lane = tid & 63, w = tid >> 6;
  att2s[tid] = att2[b * 512 + tid];
  att2s[tid + 256] = att2[b * 512 + 256 + tid];
  wfas[tid] = Wfa[tid]; wfas[tid + 256] = Wfa[tid + 256];
  __syncthreads();
  // e-scores: wave per p (49 p's per wave), lane-dot over 8 elems + shfl reduce
  float bf0 = bfa[0];
  for (int p = w; p < NP; p += 4) {
    s8v av = *(const s8v*)(att1B + ((size_t)b * NP + p) * 512 + lane * 8);
    float acc = 0.f;
#pragma unroll
    for (int i = 0; i < 8; ++i) {
      float v = b2f(av[i]) + att2s[lane * 8 + i];
      acc += fmaxf(v, 0.f) * wfas[lane * 8 + i];
    }
    for (int off = 32; off; off >>= 1) acc += __shfl_xor(acc, off, 64);
    if (lane == 0) es[p] = acc + bf0;
  }
  __syncthreads();
  // softmax over 196
  float e = (tid < NP) ? es[tid] : -1e30f;
  red[tid] = e; __syncthreads();
  for (int s = 128; s; s >>= 1) { if (tid < s) red[tid] = fmaxf(red[tid], red[tid + s]); __syncthreads(); }
  float mx = red[0]; __syncthreads();
  float ex = (tid < NP) ? expf(e - mx) : 0.f;
  red[tid] = ex; __syncthreads();
  for (int s = 128; s; s >>= 1) { if (tid < s) red[tid] += red[tid + s]; __syncthreads(); }
  float inv = 1.f / red[0];
  __syncthreads();
  es[tid] = ex * inv;                    // alpha (0 for p >= 196)
  __syncthreads();
  // awe d-quarter
  int d = dq * 512 + tid * 2;
  const short* base = encB + (size_t)b * NP * ENCD + d;
  float a0 = 0.f, a1 = 0.f;
#pragma unroll 7
  for (int p = 0; p < NP; ++p) {
    short2 vv = *(const short2*)(base + (size_t)p * ENCD);
    float a = es[p];
    a0 += a * b2f(vv.x); a1 += a * b2f(vv.y);
  }
  short2 o; o.x = f2b(a0); o.y = f2b(a1);
  *(short2*)(aweB + (size_t)b * ENCD + d) = o;
}

// ------- batched vocab projection: 8-nt B panel in 128 KiB LDS, swapped operands
// -> float4 stores. grid (250, 2), 8 waves. (R16 proven config: ~95 us)
__global__ void __launch_bounds__(512) predseq_mfma(
    const short* __restrict__ A,    // [1280][512] bf16 (rows = t*64+b)
    const short* __restrict__ Bs,   // WfcS swizzled
    const float* __restrict__ bias,
    float* __restrict__ out) {
  __shared__ short bls[16][8][64 * 8];    // 128 KiB B panel (16 ks x 8 nt)
  int tid = threadIdx.x, lane = tid & 63, wid = tid >> 6;   // 8 waves
  int ntg = blockIdx.x * 8;
  int mt0 = blockIdx.y * 10;              // 2 m-halves of 10 tiles
  int mrow = lane & 15, kq = lane >> 4;
#pragma unroll
  for (int it = 0; it < 16; ++it) {
    int ei = it * 512 + tid;
    int ks = ei >> 9, rem = ei & 511;
    int ni = rem >> 6, ln = rem & 63;
    *(s8v*)&bls[ks][ni][ln * 8] = *(const s8v*)(Bs + ((size_t)ks * 2000 + ntg + ni) * 512 + ln * 8);
  }
  __syncthreads();
  for (int mt = mt0 + wid; mt < mt0 + 10; mt += 8) {
    int m0 = mt * 64;
    f4v acc[4][8] = {};
    const short* aBase = A + (size_t)(m0 + mrow) * 512 + kq * 8;
#pragma unroll 2
    for (int ks = 0; ks < 16; ++ks) {
      s8v a[4], b[8];
#pragma unroll
      for (int mi = 0; mi < 4; ++mi) a[mi] = *(const s8v*)(aBase + mi * 16 * 512 + ks * 32);
#pragma unroll
      for (int ni = 0; ni < 8; ++ni) b[ni] = *(const s8v*)&bls[ks][ni][lane * 8];
#pragma unroll
      for (int mi = 0; mi < 4; ++mi)
#pragma unroll
        for (int ni = 0; ni < 8; ++ni)
          acc[mi][ni] = MFMA_B16(b[ni], a[mi], acc[mi][ni], 0, 0, 0);   // swapped
    }
#pragma unroll
    for (int ni = 0; ni < 8; ++ni) {
      int v0 = (ntg + ni) * 16 + kq * 4;
      float4 bv4 = *(const float4*)&bias[v0];
#pragma unroll
      for (int mi = 0; mi < 4; ++mi) {
        int row = m0 + mi * 16 + mrow;       // row = t*64 + b
        int bb = row & 63, t = row >> 6;
        float4 o4;
        o4.x = acc[mi][ni][0] + bv4.x;
        o4.y = acc[mi][ni][1] + bv4.y;
        o4.z = acc[mi][ni][2] + bv4.z;
        o4.w = acc[mi][ni][3] + bv4.w;
        *(float4*)&out[((size_t)bb * NT + t) * NV + v0] = o4;
      }
    }
  }
}

extern "C" void kernel_launch(void* const* d_in, const int* in_sizes, int n_in,
                              void* d_out, int out_size, void* d_ws, size_t ws_size,
                              hipStream_t stream) {
  const float* enc   = (const float*)d_in[0];
  const int*   caps  = (const int*)d_in[1];
  const float* emb   = (const float*)d_in[3];
  const float* Wea   = (const float*)d_in[4];
  const float* bea   = (const float*)d_in[5];
  const float* Wda   = (const float*)d_in[6];
  const float* bda   = (const float*)d_in[7];
  const float* Wfa   = (const float*)d_in[8];
  const float* bfa   = (const float*)d_in[9];
  const float* W_ih0 = (const float*)d_in[10];
  const float* W_hh0 = (const float*)d_in[11];
  const float* b_ih0 = (const float*)d_in[12];
  const float* b_hh0 = (const float*)d_in[13];
  const float* W_ih1 = (const float*)d_in[14];
  const float* W_hh1 = (const float*)d_in[15];
  const float* b_ih1 = (const float*)d_in[16];
  const float* b_hh1 = (const float*)d_in[17];
  const float* Wfc   = (const float*)d_in[18];
  const float* bfc   = (const float*)d_in[19];
  const float* Wih   = (const float*)d_in[20];
  const float* bih   = (const float*)d_in[21];
  const float* Wic   = (const float*)d_in[22];
  const float* bic   = (const float*)d_in[23];
  float* out = (float*)d_out;

  char* cw = (char*)d_ws;
  auto alloc = [&](size_t bytes) { char* p = cw; cw += (bytes + 255) & ~(size_t)255; return p; };
  short* encB  = (short*)alloc((size_t)12544 * 2048 * 2);
  short* att1B = (short*)alloc((size_t)12544 * 512 * 2);
  short* embB  = (short*)alloc((size_t)NT * NB * NE * 2);
  short* WeaS  = (short*)alloc((size_t)2048 * 512 * 2);
  short* WdaS  = (short*)alloc((size_t)512 * 512 * 2);
  short* WfcS  = (short*)alloc((size_t)512 * 32000 * 2);
  short* Wl0S  = (short*)alloc((size_t)3072 * 2048 * 2);
  short* Wl1S  = (short*)alloc((size_t)1024 * 2048 * 2);
  short* WihS  = (short*)alloc((size_t)2048 * 512 * 2);
  short* WicS  = (short*)alloc((size_t)2048 * 512 * 2);
  short* meB   = (short*)alloc((size_t)64 * 2048 * 2);
  float* bsum0 = (float*)alloc(2048 * 4);
  float* bsum1 = (float*)alloc(2048 * 4);
  float* att2  = (float*)alloc((size_t)64 * 512 * 4);
  short* h0b[2] = { (short*)alloc(64 * 512 * 2), (short*)alloc(64 * 512 * 2) };
  short* h1init = (short*)alloc(64 * 512 * 2);
  short* h1seq  = (short*)alloc((size_t)NT * 64 * 512 * 2);   // [t*64+b][k]
  float* c0 = (float*)alloc(64 * 512 * 4);
  float* c1 = (float*)alloc(64 * 512 * 4);
  short* aweB = (short*)alloc((size_t)64 * 2048 * 2);

  // ---- one-time precompute ----
  conv_mean<<<256, 256, 0, stream>>>(enc, encB, meB);
  emb_b16<<<NT * NB, 256, 0, stream>>>(caps, emb, embB);
  swz_rm<<<dim3(64, 2), 256, 0, stream>>>(Wea, 512, WeaS);
  swz_rm<<<dim3(16, 2), 256, 0, stream>>>(Wda, 512, WdaS);
  swz_rm<<<dim3(16, 125), 256, 0, stream>>>(Wfc, 32000, WfcS);
  swz_rm2<<<dim3(64, 2, 2), 256, 0, stream>>>(Wih, WihS, Wic, WicS);
  swz_lstm<<<dim3(96, 32), 256, 0, stream>>>(W_ih0, 2560, W_hh0, Wl0S);
  swz_lstm<<<dim3(32, 32), 256, 0, stream>>>(W_ih1, 512, W_hh1, Wl1S);
  bias_sum2<<<16, 256, 0, stream>>>(b_ih0, b_hh0, bsum0, b_ih1, b_hh1, bsum1);
  att1_tiled<<<196, 256, 0, stream>>>(encB, WeaS, bea, att1B);
  init_mfma<<<dim3(4, 64), 64, 0, stream>>>(meB, WihS, WicS, bih, bic,
                                            h0b[0], h1init, c0, c1);

  const short* h1prev = h1init;
  int cur = 0;
  for (int t = 0; t < NT; ++t) {
    int nxt = cur ^ 1;
    att2_mfma<<<32, 256, 0, stream>>>(h1prev, WdaS, bda, att2);
    esc_smax_awe<<<NB * 4, 256, 0, stream>>>(att1B, att2, Wfa, bfa, encB, aweB);
    lstm_t<512, 2048, 512><<<dim3(32, 4), 512, 0, stream>>>(
        embB + (size_t)t * NB * NE, aweB, h0b[cur],
        Wl0S, bsum0, c0, h0b[nxt]);
    short* h1out = h1seq + (size_t)t * NB * HIDD;
    lstm_t<512, 512, 0><<<dim3(32, 4), 512, 0, stream>>>(
        h0b[nxt], h1prev, nullptr,
        Wl1S, bsum1, c1, h1out);
    h1prev = h1out;
    cur = nxt;
  }
  predseq_mfma<<<dim3(250, 2), 512, 0, stream>>>(h1seq, WfcS, bfc, out);
}

// Round 20
// 1352.837 us; speedup vs baseline: 1.2588x; 1.2588x over previous
//
#include <hip/hip_runtime.h>

#define ENCD 2048
#define ATTD 512
#define HIDD 512
#define NB 64
#define NP 196
#define NT 20
#define NV 32000
#define NE 512

using s8v = __attribute__((ext_vector_type(8))) short;   // 8 bf16 (4 VGPRs)
using f4v = __attribute__((ext_vector_type(4))) float;   // 4 f32 acc
#define MFMA_B16 __builtin_amdgcn_mfma_f32_16x16x32_bf16

__device__ inline short f2b(float f) {
  union { float f; unsigned u; } v; v.f = f;
  unsigned r = v.u + 0x7fff + ((v.u >> 16) & 1);
  return (short)(r >> 16);
}
__device__ inline float b2f(short s) {
  union { unsigned u; float f; } v; v.u = ((unsigned)(unsigned short)s) << 16;
  return v.f;
}

// ------- fused: enc f32 -> encB bf16, and mean over P -> meB[b][k] -------
__global__ void conv_mean(const float* __restrict__ enc, short* __restrict__ encB,
                          short* __restrict__ meB) {
  int b = blockIdx.x >> 2, kq = blockIdx.x & 3;
  int k = kq * 512 + threadIdx.x * 2;
  const float* src = enc + (size_t)b * NP * ENCD + k;
  short* dst = encB + (size_t)b * NP * ENCD + k;
  float a0 = 0.f, a1 = 0.f;
  for (int p = 0; p < NP; ++p) {
    float2 v = *(const float2*)(src + (size_t)p * ENCD);
    a0 += v.x; a1 += v.y;
    short2 o; o.x = f2b(v.x); o.y = f2b(v.y);
    *(short2*)(dst + (size_t)p * ENCD) = o;
  }
  short2 m; m.x = f2b(a0 * (1.f / NP)); m.y = f2b(a1 * (1.f / NP));
  *(short2*)(meB + (size_t)b * ENCD + k) = m;
}

// ---------------- embedding gather -> bf16 row-major embB[t][b][k] ----------------
__global__ void emb_b16(const int* __restrict__ caps, const float* __restrict__ emb,
                        short* __restrict__ embB) {
  int t = blockIdx.x / NB, b = blockIdx.x % NB;
  int cap = caps[b * NT + t];
  int k = threadIdx.x;
  for (int r = 0; r < 2; ++r, k += 256)
    embB[((size_t)t * NB + b) * NE + k] = f2b(emb[(size_t)cap * NE + k]);
}

// ---- swizzle builder: B[k][n] f32 row-major (ld = N) -> MFMA b-frag layout
__global__ void swz_rm(const float* __restrict__ B, int N, short* __restrict__ dst) {
  __shared__ short lt[256 * 32];          // [n within chunk][k]
  int tid = threadIdx.x;
  int k0 = blockIdx.x * 32, n0 = blockIdx.y * 256;
  for (int k = 0; k < 32; ++k)
    lt[tid * 32 + k] = f2b(B[(size_t)(k0 + k) * N + n0 + tid]);
  __syncthreads();
  int NT16 = N >> 4;
  for (int r = 0; r < 4; ++r) {
    int idx = r * 256 + tid;
    int lane = idx & 63, ntl = idx >> 6;
    int srcn = ntl * 16 + (lane & 15), srck = (lane >> 4) * 8;
    short* o = dst + ((size_t)blockIdx.x * NT16 + (n0 >> 4) + ntl) * 512 + lane * 8;
    for (int i = 0; i < 8; ++i) o[i] = lt[srcn * 32 + srck + i];
  }
}

// ---- two 2048x512 swizzles in one dispatch (z selects src/dst) ----
__global__ void swz_rm2(const float* __restrict__ B0, short* __restrict__ D0,
                        const float* __restrict__ B1, short* __restrict__ D1) {
  __shared__ short lt[256 * 32];
  const float* B = blockIdx.z ? B1 : B0;
  short* dst = blockIdx.z ? D1 : D0;
  int tid = threadIdx.x;
  int k0 = blockIdx.x * 32, n0 = blockIdx.y * 256;
  for (int k = 0; k < 32; ++k)
    lt[tid * 32 + k] = f2b(B[(size_t)(k0 + k) * 512 + n0 + tid]);
  __syncthreads();
  for (int r = 0; r < 4; ++r) {
    int idx = r * 256 + tid;
    int lane = idx & 63, ntl = idx >> 6;
    int srcn = ntl * 16 + (lane & 15), srck = (lane >> 4) * 8;
    short* o = dst + ((size_t)blockIdx.x * 32 + (n0 >> 4) + ntl) * 512 + lane * 8;
    for (int i = 0; i < 8; ++i) o[i] = lt[srcn * 32 + srck + i];
  }
}

// ---- LSTM combined weight swizzle ----
__global__ void swz_lstm(const float* __restrict__ Wih, int Kih, const float* __restrict__ Whh,
                         short* __restrict__ dst) {
  int tid = threadIdx.x, lane = tid & 63;
  int ct = blockIdx.y * 4 + (tid >> 6);
  int n = ct * 16 + (lane & 15);
  int k = blockIdx.x * 32 + ((lane >> 4) << 3);
  short* o = dst + ((size_t)blockIdx.x * 128 + ct) * 512 + lane * 8;
  for (int i = 0; i < 8; ++i) {
    int kk = k + i;
    float f = (kk < Kih) ? Wih[(size_t)n * Kih + kk] : Whh[(size_t)n * 512 + (kk - Kih)];
    o[i] = f2b(f);
  }
}

// ---- both bias sums in one dispatch ----
__global__ void bias_sum2(const float* __restrict__ a0, const float* __restrict__ b0,
                          float* __restrict__ o0,
                          const float* __restrict__ a1, const float* __restrict__ b1,
                          float* __restrict__ o1) {
  int i = (blockIdx.x & 7) * 256 + threadIdx.x;
  if (blockIdx.x < 8) o0[i] = a0[i] + b0[i];
  else                o1[i] = a1[i] + b1[i];
}

// ------- att1 = encB @ WeaS + bea -> bf16 [12544][512] -------
// 196 blocks (one 64-row A panel each, read ONCE), LDS double-buffered A
__global__ void __launch_bounds__(256) att1_tiled(
    const short* __restrict__ A, const short* __restrict__ Bs,
    const float* __restrict__ bias, short* __restrict__ att1B) {
  __shared__ short as[2][64][40];         // padded: row stride 80B -> 2-way bank alias only
  int tid = threadIdx.x, lane = tid & 63, w = tid >> 6;
  int m0 = blockIdx.x * 64;
  int mrow = lane & 15, kq = lane >> 4;
  int sr = tid >> 2, sc = (tid & 3) * 8;
  f4v acc[4][8] = {};
  *(s8v*)&as[0][sr][sc] = *(const s8v*)(A + (size_t)(m0 + sr) * 2048 + sc);
  __syncthreads();
  for (int ks = 0; ks < 64; ++ks) {
    int cur = ks & 1;
    if (ks < 63)
      *(s8v*)&as[cur ^ 1][sr][sc] = *(const s8v*)(A + (size_t)(m0 + sr) * 2048 + (ks + 1) * 32 + sc);
    s8v a[4], b[8];
#pragma unroll
    for (int mi = 0; mi < 4; ++mi)
      a[mi] = *(const s8v*)&as[cur][mi * 16 + mrow][kq * 8];
#pragma unroll
    for (int ni = 0; ni < 8; ++ni)
      b[ni] = *(const s8v*)(Bs + ((size_t)ks * 32 + w * 8 + ni) * 512 + lane * 8);
#pragma unroll
    for (int mi = 0; mi < 4; ++mi)
#pragma unroll
      for (int ni = 0; ni < 8; ++ni)
        acc[mi][ni] = MFMA_B16(a[mi], b[ni], acc[mi][ni], 0, 0, 0);
    __syncthreads();
  }
#pragma unroll
  for (int mi = 0; mi < 4; ++mi)
#pragma unroll
    for (int ni = 0; ni < 8; ++ni) {
      int col = (w * 8 + ni) * 16 + mrow;
      int rbase = m0 + mi * 16 + kq * 4;
      float bv = bias[col];
      for (int r = 0; r < 4; ++r)
        att1B[(size_t)(rbase + r) * 512 + col] = f2b(acc[mi][ni][r] + bv);
    }
}

// ---- init h/c via MFMA ----
__global__ void init_mfma(const short* __restrict__ A,
                          const short* __restrict__ BsH, const short* __restrict__ BsC,
                          const float* __restrict__ bih, const float* __restrict__ bic,
                          short* __restrict__ h0, short* __restrict__ h1,
                          float* __restrict__ c0v, float* __restrict__ c1v) {
  int lane = threadIdx.x & 63;
  int mi = blockIdx.x, jt0 = blockIdx.y;
  bool isC = jt0 >= 32;
  int jt = jt0 & 31;
  const short* Bs = isC ? BsC : BsH;
  int mrow = lane & 15, kq = lane >> 4;
  f4v acc = {};
  const short* aBase = A + (size_t)(mi * 16 + mrow) * 2048 + kq * 8;
  const short* bBase = Bs + lane * 8;
#pragma unroll 4
  for (int ks = 0; ks < 64; ++ks) {
    s8v a = *(const s8v*)(aBase + ks * 32);
    s8v b = *(const s8v*)(bBase + ((size_t)ks * 32 + jt) * 512);
    acc = MFMA_B16(a, b, acc, 0, 0, 0);
  }
  int j = jt * 16 + mrow;
  float bv = (isC ? bic : bih)[j];
  for (int r = 0; r < 4; ++r) {
    int b = mi * 16 + kq * 4 + r;
    size_t idx = (size_t)b * 512 + j;
    float o = acc[r] + bv;
    if (isC) { c0v[idx] = o; c1v[idx] = o; }
    else     { short s = f2b(o); h0[idx] = s; h1[idx] = s; }
  }
}

// ---- compile-time K-segment for the LSTM gates GEMM (enables unroll/pipelining) ----
template<int KSEG, int KBASE>
__device__ __forceinline__ void seg_mm(const short* __restrict__ aRow, int kh, int kq,
                                       int ct, const short* __restrict__ bBase, f4v& acc) {
  constexpr int HALF = KSEG / 2;
  const int kl0 = kh * HALF;
#pragma unroll 4
  for (int i = 0; i < HALF / 32; ++i) {
    int kl = kl0 + i * 32;
    s8v a = *(const s8v*)(aRow + kl + kq * 8);
    int ksi = (KBASE + kl) >> 5;
    s8v b = *(const s8v*)(bBase + ((size_t)ksi * 128 + ct) * 512);
    acc = MFMA_B16(a, b, acc, 0, 0, 0);
  }
}

// ------- fused LSTM: 8-wave (gate g x k-half kh) split-K; 512 thr; templated K -------
// grid(32, 4): jt = x (fastest) so same-B blocks land on the same XCD.
template<int K1, int K2, int K3>
__global__ void __launch_bounds__(512) lstm_t(
    const short* __restrict__ A1, const short* __restrict__ A2,
    const short* __restrict__ A3,
    const short* __restrict__ Bs, const float* __restrict__ bias,
    float* __restrict__ c_st, short* __restrict__ h_out) {
  __shared__ f4v gsh[8][64];
  int tid = threadIdx.x, lane = tid & 63, w = tid >> 6;
  int g = w >> 1, kh = w & 1;
  int jt = blockIdx.x, mi = blockIdx.y;
  int mrow = lane & 15, kq = lane >> 4;
  int m = mi * 16 + mrow;
  int ct = g * 32 + jt;
  f4v acc = {};
  const short* bBase = Bs + lane * 8;
  seg_mm<K1, 0>(A1 + (size_t)m * K1, kh, kq, ct, bBase, acc);
  seg_mm<K2, K1>(A2 + (size_t)m * K2, kh, kq, ct, bBase, acc);
  if constexpr (K3 > 0)
    seg_mm<K3, K1 + K2>(A3 + (size_t)m * K3, kh, kq, ct, bBase, acc);
  gsh[w][lane] = acc;
  __syncthreads();
  if (tid < 256) {
    int b_l = tid >> 4, j_l = tid & 15;
    int lsrc = (b_l >> 2) * 16 + j_l, r = b_l & 3;
    int j = jt * 16 + j_l;
    float ii = gsh[0][lsrc][r] + gsh[1][lsrc][r] + bias[j];
    float ff = gsh[2][lsrc][r] + gsh[3][lsrc][r] + bias[512 + j];
    float gg = gsh[4][lsrc][r] + gsh[5][lsrc][r] + bias[1024 + j];
    float oo = gsh[6][lsrc][r] + gsh[7][lsrc][r] + bias[1536 + j];
    size_t idx = (size_t)(mi * 16 + b_l) * 512 + j;
    float c_old = c_st[idx];
    float si = 1.f / (1.f + expf(-ii));
    float sf = 1.f / (1.f + expf(-ff));
    float so = 1.f / (1.f + expf(-oo));
    float cn = sf * c_old + si * tanhf(gg);
    c_st[idx] = cn;
    h_out[idx] = f2b(so * tanhf(cn));
  }
}

// ------- att2 = h1 @ WdaS + bda -> f32 [64][512]; 256-thr, wave = mi -------
__global__ void att2_mfma(const short* __restrict__ A, const short* __restrict__ Bs,
                          const float* __restrict__ bias, float* __restrict__ C) {
  int tid = threadIdx.x, lane = tid & 63, mi = tid >> 6;
  int nt = blockIdx.x;
  int mrow = lane & 15, kq = lane >> 4;
  f4v acc = {};
  const short* aBase = A + (size_t)(mi * 16 + mrow) * 512 + kq * 8;
  const short* bBase = Bs + lane * 8;
#pragma unroll
  for (int ks = 0; ks < 16; ++ks) {
    s8v a = *(const s8v*)(aBase + ks * 32);
    s8v b = *(const s8v*)(bBase + ((size_t)ks * 32 + nt) * 512);
    acc = MFMA_B16(a, b, acc, 0, 0, 0);
  }
  int col = nt * 16 + mrow;
  float bv = bias[col];
  for (int r = 0; r < 4; ++r) C[(size_t)(mi * 16 + kq * 4 + r) * 512 + col] = acc[r] + bv;
}

// ------- e-scores at 256 blocks (b x 4 p-quarters); att2/Wfa slices in registers -------
__global__ void esc_kernel(const short* __restrict__ att1B, const float* __restrict__ att2,
                           const float* __restrict__ Wfa, const float* __restrict__ bfa,
                           float* __restrict__ eG) {
  int b = blockIdx.x >> 2, pq = blockIdx.x & 3;
  int tid = threadIdx.x, lane = tid & 63, w = tid >> 6;
  float a2[8], wf[8];
  const float* a2p = att2 + b * 512 + lane * 8;
  const float* wfp = Wfa + lane * 8;
#pragma unroll
  for (int i = 0; i < 8; ++i) { a2[i] = a2p[i]; wf[i] = wfp[i]; }
  float bf0 = bfa[0];
  int p0 = pq * 49;
  for (int p = p0 + w; p < p0 + 49; p += 4) {
    s8v av = *(const s8v*)(att1B + ((size_t)b * NP + p) * 512 + lane * 8);
    float acc = 0.f;
#pragma unroll
    for (int i = 0; i < 8; ++i) {
      float v = b2f(av[i]) + a2[i];
      acc += fmaxf(v, 0.f) * wf[i];
    }
    for (int off = 32; off; off >>= 1) acc += __shfl_xor(acc, off, 64);
    if (lane == 0) eG[b * 256 + p] = acc + bf0;
  }
}

// ------- softmax over 196 (redundant x4, trivial) + awe d-quarter; grid 256 -------
__global__ void smax_awe(const float* __restrict__ eG, const short* __restrict__ encB,
                         short* __restrict__ aweB) {
  __shared__ float red[256];
  __shared__ float alpha[256];
  int b = blockIdx.x >> 2, dq = blockIdx.x & 3, tid = threadIdx.x;
  float e = (tid < NP) ? eG[b * 256 + tid] : -1e30f;
  red[tid] = e; __syncthreads();
  for (int s = 128; s; s >>= 1) { if (tid < s) red[tid] = fmaxf(red[tid], red[tid + s]); __syncthreads(); }
  float mx = red[0]; __syncthreads();
  float ex = (tid < NP) ? expf(e - mx) : 0.f;
  red[tid] = ex; __syncthreads();
  for (int s = 128; s; s >>= 1) { if (tid < s) red[tid] += red[tid + s]; __syncthreads(); }
  float inv = 1.f / red[0];
  alpha[tid] = ex * inv;
  __syncthreads();
  int d = dq * 512 + tid * 2;
  const short* base = encB + (size_t)b * NP * ENCD + d;
  float a0 = 0.f, a1 = 0.f;
#pragma unroll 7
  for (int p = 0; p < NP; ++p) {
    short2 vv = *(const short2*)(base + (size_t)p * ENCD);
    float a = alpha[p];
    a0 += a * b2f(vv.x); a1 += a * b2f(vv.y);
  }
  short2 o; o.x = f2b(a0); o.y = f2b(a1);
  *(short2*)(aweB + (size_t)b * ENCD + d) = o;
}

// ------- batched vocab projection: 8-nt B panel in 128 KiB LDS, swapped operands
// -> float4 stores. grid (250, 2), 8 waves. (R16 proven config: ~95 us)
__global__ void __launch_bounds__(512) predseq_mfma(
    const short* __restrict__ A,    // [1280][512] bf16 (rows = t*64+b)
    const short* __restrict__ Bs,   // WfcS swizzled
    const float* __restrict__ bias,
    float* __restrict__ out) {
  __shared__ short bls[16][8][64 * 8];    // 128 KiB B panel (16 ks x 8 nt)
  int tid = threadIdx.x, lane = tid & 63, wid = tid >> 6;   // 8 waves
  int ntg = blockIdx.x * 8;
  int mt0 = blockIdx.y * 10;              // 2 m-halves of 10 tiles
  int mrow = lane & 15, kq = lane >> 4;
#pragma unroll
  for (int it = 0; it < 16; ++it) {
    int ei = it * 512 + tid;
    int ks = ei >> 9, rem = ei & 511;
    int ni = rem >> 6, ln = rem & 63;
    *(s8v*)&bls[ks][ni][ln * 8] = *(const s8v*)(Bs + ((size_t)ks * 2000 + ntg + ni) * 512 + ln * 8);
  }
  __syncthreads();
  for (int mt = mt0 + wid; mt < mt0 + 10; mt += 8) {
    int m0 = mt * 64;
    f4v acc[4][8] = {};
    const short* aBase = A + (size_t)(m0 + mrow) * 512 + kq * 8;
#pragma unroll 2
    for (int ks = 0; ks < 16; ++ks) {
      s8v a[4], b[8];
#pragma unroll
      for (int mi = 0; mi < 4; ++mi) a[mi] = *(const s8v*)(aBase + mi * 16 * 512 + ks * 32);
#pragma unroll
      for (int ni = 0; ni < 8; ++ni) b[ni] = *(const s8v*)&bls[ks][ni][lane * 8];
#pragma unroll
      for (int mi = 0; mi < 4; ++mi)
#pragma unroll
        for (int ni = 0; ni < 8; ++ni)
          acc[mi][ni] = MFMA_B16(b[ni], a[mi], acc[mi][ni], 0, 0, 0);   // swapped
    }
#pragma unroll
    for (int ni = 0; ni < 8; ++ni) {
      int v0 = (ntg + ni) * 16 + kq * 4;
      float4 bv4 = *(const float4*)&bias[v0];
#pragma unroll
      for (int mi = 0; mi < 4; ++mi) {
        int row = m0 + mi * 16 + mrow;       // row = t*64 + b
        int bb = row & 63, t = row >> 6;
        float4 o4;
        o4.x = acc[mi][ni][0] + bv4.x;
        o4.y = acc[mi][ni][1] + bv4.y;
        o4.z = acc[mi][ni][2] + bv4.z;
        o4.w = acc[mi][ni][3] + bv4.w;
        *(float4*)&out[((size_t)bb * NT + t) * NV + v0] = o4;
      }
    }
  }
}

extern "C" void kernel_launch(void* const* d_in, const int* in_sizes, int n_in,
                              void* d_out, int out_size, void* d_ws, size_t ws_size,
                              hipStream_t stream) {
  const float* enc   = (const float*)d_in[0];
  const int*   caps  = (const int*)d_in[1];
  const float* emb   = (const float*)d_in[3];
  const float* Wea   = (const float*)d_in[4];
  const float* bea   = (const float*)d_in[5];
  const float* Wda   = (const float*)d_in[6];
  const float* bda   = (const float*)d_in[7];
  const float* Wfa   = (const float*)d_in[8];
  const float* bfa   = (const float*)d_in[9];
  const float* W_ih0 = (const float*)d_in[10];
  const float* W_hh0 = (const float*)d_in[11];
  const float* b_ih0 = (const float*)d_in[12];
  const float* b_hh0 = (const float*)d_in[13];
  const float* W_ih1 = (const float*)d_in[14];
  const float* W_hh1 = (const float*)d_in[15];
  const float* b_ih1 = (const float*)d_in[16];
  const float* b_hh1 = (const float*)d_in[17];
  const float* Wfc   = (const float*)d_in[18];
  const float* bfc   = (const float*)d_in[19];
  const float* Wih   = (const float*)d_in[20];
  const float* bih   = (const float*)d_in[21];
  const float* Wic   = (const float*)d_in[22];
  const float* bic   = (const float*)d_in[23];
  float* out = (float*)d_out;

  char* cw = (char*)d_ws;
  auto alloc = [&](size_t bytes) { char* p = cw; cw += (bytes + 255) & ~(size_t)255; return p; };
  short* encB  = (short*)alloc((size_t)12544 * 2048 * 2);
  short* att1B = (short*)alloc((size_t)12544 * 512 * 2);
  short* embB  = (short*)alloc((size_t)NT * NB * NE * 2);
  short* WeaS  = (short*)alloc((size_t)2048 * 512 * 2);
  short* WdaS  = (short*)alloc((size_t)512 * 512 * 2);
  short* WfcS  = (short*)alloc((size_t)512 * 32000 * 2);
  short* Wl0S  = (short*)alloc((size_t)3072 * 2048 * 2);
  short* Wl1S  = (short*)alloc((size_t)1024 * 2048 * 2);
  short* WihS  = (short*)alloc((size_t)2048 * 512 * 2);
  short* WicS  = (short*)alloc((size_t)2048 * 512 * 2);
  short* meB   = (short*)alloc((size_t)64 * 2048 * 2);
  float* bsum0 = (float*)alloc(2048 * 4);
  float* bsum1 = (float*)alloc(2048 * 4);
  float* att2  = (float*)alloc((size_t)64 * 512 * 4);
  float* eG    = (float*)alloc((size_t)64 * 256 * 4);
  short* h0b[2] = { (short*)alloc(64 * 512 * 2), (short*)alloc(64 * 512 * 2) };
  short* h1init = (short*)alloc(64 * 512 * 2);
  short* h1seq  = (short*)alloc((size_t)NT * 64 * 512 * 2);   // [t*64+b][k]
  float* c0 = (float*)alloc(64 * 512 * 4);
  float* c1 = (float*)alloc(64 * 512 * 4);
  short* aweB = (short*)alloc((size_t)64 * 2048 * 2);

  // ---- one-time precompute ----
  conv_mean<<<256, 256, 0, stream>>>(enc, encB, meB);
  emb_b16<<<NT * NB, 256, 0, stream>>>(caps, emb, embB);
  swz_rm<<<dim3(64, 2), 256, 0, stream>>>(Wea, 512, WeaS);
  swz_rm<<<dim3(16, 2), 256, 0, stream>>>(Wda, 512, WdaS);
  swz_rm<<<dim3(16, 125), 256, 0, stream>>>(Wfc, 32000, WfcS);
  swz_rm2<<<dim3(64, 2, 2), 256, 0, stream>>>(Wih, WihS, Wic, WicS);
  swz_lstm<<<dim3(96, 32), 256, 0, stream>>>(W_ih0, 2560, W_hh0, Wl0S);
  swz_lstm<<<dim3(32, 32), 256, 0, stream>>>(W_ih1, 512, W_hh1, Wl1S);
  bias_sum2<<<16, 256, 0, stream>>>(b_ih0, b_hh0, bsum0, b_ih1, b_hh1, bsum1);
  att1_tiled<<<196, 256, 0, stream>>>(encB, WeaS, bea, att1B);
  init_mfma<<<dim3(4, 64), 64, 0, stream>>>(meB, WihS, WicS, bih, bic,
                                            h0b[0], h1init, c0, c1);

  const short* h1prev = h1init;
  int cur = 0;
  for (int t = 0; t < NT; ++t) {
    int nxt = cur ^ 1;
    att2_mfma<<<32, 256, 0, stream>>>(h1prev, WdaS, bda, att2);
    esc_kernel<<<NB * 4, 256, 0, stream>>>(att1B, att2, Wfa, bfa, eG);
    smax_awe<<<NB * 4, 256, 0, stream>>>(eG, encB, aweB);
    lstm_t<512, 2048, 512><<<dim3(32, 4), 512, 0, stream>>>(
        embB + (size_t)t * NB * NE, aweB, h0b[cur],
        Wl0S, bsum0, c0, h0b[nxt]);
    short* h1out = h1seq + (size_t)t * NB * HIDD;
    lstm_t<512, 512, 0><<<dim3(32, 4), 512, 0, stream>>>(
        h0b[nxt], h1prev, nullptr,
        Wl1S, bsum1, c1, h1out);
    h1prev = h1out;
    cur = nxt;
  }
  predseq_mfma<<<dim3(250, 2), 512, 0, stream>>>(h1seq, WfcS, bfc, out);
}